// Round 1
// baseline (743.112 us; speedup 1.0000x reference)
//
#include <hip/hip_runtime.h>
#include <hip/hip_bf16.h>

typedef __attribute__((ext_vector_type(8))) short short8;
typedef __attribute__((ext_vector_type(4))) float f32x4;

#define DEVI static __device__ __forceinline__

DEVI ushort f2bf(float f) {
  union { __hip_bfloat16 h; ushort u; } c; c.h = __float2bfloat16(f); return c.u;
}
DEVI float bf2f(ushort u) {
  union { __hip_bfloat16 h; ushort u; } c; c.u = u; return __bfloat162float(c.h);
}

// block-wide (256 threads) reduction of two values
DEVI void blk_reduce2(float& a, float& b) {
  #pragma unroll
  for (int m = 1; m < 64; m <<= 1) {
    a += __shfl_xor(a, m);
    b += __shfl_xor(b, m);
  }
  __shared__ float sc[8];
  int tid = threadIdx.x, w = tid >> 6;
  if ((tid & 63) == 0) { sc[w * 2] = a; sc[w * 2 + 1] = b; }
  __syncthreads();
  if (tid == 0) {
    sc[0] = sc[0] + sc[2] + sc[4] + sc[6];
    sc[1] = sc[1] + sc[3] + sc[5] + sc[7];
  }
  __syncthreads();
  a = sc[0]; b = sc[1];
  __syncthreads();
}

// ---------------- weight transpose (f32 [k][n] -> bf16 [n][k]) + zero bstats ----
__global__ void kw_kernel(const float* w0, const float* w1, const float* w2, const float* w3,
                          ushort* wT, float* bstats) {
  int widx = blockIdx.y;
  const float* src = (widx == 0) ? w0 : (widx == 1) ? w1 : (widx == 2) ? w2 : w3;
  ushort* dst = wT + (size_t)widx * 65536;
  int tile = blockIdx.x;               // 0..15
  int k0 = (tile >> 2) * 64, n0 = (tile & 3) * 64;
  __shared__ float t[64][65];
  int tid = threadIdx.x;
  int r = tid >> 2, c0 = (tid & 3) * 16;
  #pragma unroll
  for (int j = 0; j < 16; j += 4) {
    float4 v = *reinterpret_cast<const float4*>(src + (size_t)(k0 + r) * 256 + n0 + c0 + j);
    t[r][c0 + j + 0] = v.x; t[r][c0 + j + 1] = v.y;
    t[r][c0 + j + 2] = v.z; t[r][c0 + j + 3] = v.w;
  }
  __syncthreads();
  ushort buf[16];
  #pragma unroll
  for (int j = 0; j < 16; j++) buf[j] = f2bf(t[c0 + j][r]);
  size_t o = (size_t)(n0 + r) * 256 + k0 + c0;
  *reinterpret_cast<uint4*>(dst + o) = *reinterpret_cast<uint4*>(&buf[0]);
  *reinterpret_cast<uint4*>(dst + o + 8) = *reinterpret_cast<uint4*>(&buf[8]);
  if (blockIdx.x == 0 && blockIdx.y == 0 && tid < 64) bstats[tid] = 0.f;
}

// ---------------- batch stats: sum, sumsq of h = x + pos over [D,NTOK] ---------
__global__ void k1_stats(const float* x, const float* pos_w, const float* pos_b, float* bstats) {
  int b = blockIdx.y, blk = blockIdx.x, tid = threadIdx.x;
  const float* xb = x + (size_t)b * 1048576;
  float s = 0.f, sq = 0.f;
  for (int i = 0; i < 16; i++) {
    int e4 = blk * 4096 + i * 256 + tid;   // float4 index within batch
    int e = e4 * 4;
    int d = e >> 12, t = e & 4095;
    int ii = t >> 6, j0 = t & 63;
    float xx = ii * (1.f / 63.f);
    float c0 = pos_w[512 + d] + pos_w[768 + d] + pos_b[d];
    float cx = pos_w[d] - pos_w[512 + d];
    float cy = pos_w[256 + d] - pos_w[768 + d];
    float4 v = reinterpret_cast<const float4*>(xb)[e4];
    float base = c0 + xx * cx;
    #pragma unroll
    for (int j = 0; j < 4; j++) {
      float yy = (j0 + j) * (1.f / 63.f);
      float h = (&v.x)[j] + base + yy * cy;
      s += h; sq += h * h;
    }
  }
  blk_reduce2(s, sq);
  if (tid == 0) {
    atomicAdd(&bstats[b * 2], s);
    atomicAdd(&bstats[b * 2 + 1], sq);
  }
}

// ---------------- tokens: transpose + batch-LN + enc affine -> bf16 [B*NTOK][D] -
__global__ void k2_tokens(const float* x, const float* pos_w, const float* pos_b,
                          const float* enc_g, const float* enc_b, const float* bstats,
                          ushort* t0) {
  int tcx = blockIdx.x;   // i index (token row block), 0..63
  int dcx = blockIdx.y;   // 0..3
  int b = blockIdx.z;
  int tid = threadIdx.x;
  float mean = bstats[b * 2] * (1.f / 1048576.f);
  float var = bstats[b * 2 + 1] * (1.f / 1048576.f) - mean * mean;
  float rstd = rsqrtf(var + 1e-5f);
  __shared__ float tt[64][65];          // [t_local][d_local]
  const float* xb = x + (size_t)b * 1048576;
  float xx = tcx * (1.f / 63.f);
  #pragma unroll
  for (int it = 0; it < 4; it++) {
    int idx = tid + it * 256;
    int dl = idx >> 4, f4 = idx & 15;
    int d = dcx * 64 + dl;
    float c0 = pos_w[512 + d] + pos_w[768 + d] + pos_b[d];
    float cx = pos_w[d] - pos_w[512 + d];
    float cy = pos_w[256 + d] - pos_w[768 + d];
    float4 v = *reinterpret_cast<const float4*>(xb + (size_t)d * 4096 + tcx * 64 + f4 * 4);
    float base = c0 + xx * cx;
    #pragma unroll
    for (int j = 0; j < 4; j++) {
      float yy = (f4 * 4 + j) * (1.f / 63.f);
      tt[f4 * 4 + j][dl] = (&v.x)[j] + base + yy * cy;
    }
  }
  __syncthreads();
  int t_l = tid >> 2, dc = (tid & 3) * 16;
  int t = tcx * 64 + t_l;
  ushort ob[16];
  #pragma unroll
  for (int j = 0; j < 16; j++) {
    int d = dcx * 64 + dc + j;
    float h = (tt[t_l][dc + j] - mean) * rstd;
    h = h * enc_g[(size_t)t * 256 + d] + enc_b[(size_t)t * 256 + d];
    ob[j] = f2bf(h);
  }
  size_t o = (size_t)(b * 4096 + t) * 256 + dcx * 64 + dc;
  *reinterpret_cast<uint4*>(t0 + o) = *reinterpret_cast<uint4*>(&ob[0]);
  *reinterpret_cast<uint4*>(t0 + o + 8) = *reinterpret_cast<uint4*>(&ob[8]);
}

// ---------------- GEMM: C[M x 256] = act(A[M x 256] @ W + bias), bf16 ----------
// A row-major bf16; WT is W^T (bf16, [n][k]); full 256-col rows per block => in-place safe.
template <bool RELU>
__global__ __launch_bounds__(512) void gemm_kernel(const ushort* __restrict__ A,
                                                   const ushort* __restrict__ WT,
                                                   const float* __restrict__ bias,
                                                   ushort* __restrict__ C) {
  __shared__ ushort As[128 * 72];
  __shared__ ushort Bs[256 * 72];
  int tid = threadIdx.x;
  int r0 = blockIdx.x * 128;
  int w = tid >> 6, lane = tid & 63;
  int wr = w >> 2, wc = w & 3;        // 2 x 4 waves, each 64(M) x 64(N)
  f32x4 acc[4][4];
  #pragma unroll
  for (int m = 0; m < 4; m++)
    #pragma unroll
    for (int n = 0; n < 4; n++) acc[m][n] = (f32x4)(0.f);

  for (int ks = 0; ks < 4; ks++) {
    int k0 = ks * 64;
    __syncthreads();
    #pragma unroll
    for (int i = 0; i < 2; i++) {     // A tile: 128 rows x 64 k
      int idx = tid + i * 512;
      int r = idx >> 3, cc = idx & 7;
      uint4 v = *reinterpret_cast<const uint4*>(A + (size_t)(r0 + r) * 256 + k0 + cc * 8);
      *reinterpret_cast<uint4*>(&As[r * 72 + cc * 8]) = v;
    }
    #pragma unroll
    for (int i = 0; i < 4; i++) {     // B tile: 256 n-rows x 64 k
      int idx = tid + i * 512;
      int r = idx >> 3, cc = idx & 7;
      uint4 v = *reinterpret_cast<const uint4*>(WT + (size_t)r * 256 + k0 + cc * 8);
      *reinterpret_cast<uint4*>(&Bs[r * 72 + cc * 8]) = v;
    }
    __syncthreads();
    #pragma unroll
    for (int ksub = 0; ksub < 2; ksub++) {
      int kk = ksub * 32 + (lane >> 4) * 8;
      short8 af[4], bf[4];
      #pragma unroll
      for (int m = 0; m < 4; m++)
        af[m] = *reinterpret_cast<const short8*>(&As[(wr * 64 + m * 16 + (lane & 15)) * 72 + kk]);
      #pragma unroll
      for (int n = 0; n < 4; n++)
        bf[n] = *reinterpret_cast<const short8*>(&Bs[(wc * 64 + n * 16 + (lane & 15)) * 72 + kk]);
      #pragma unroll
      for (int m = 0; m < 4; m++)
        #pragma unroll
        for (int n = 0; n < 4; n++)
          acc[m][n] = __builtin_amdgcn_mfma_f32_16x16x32_bf16(af[m], bf[n], acc[m][n], 0, 0, 0);
    }
  }
  #pragma unroll
  for (int m = 0; m < 4; m++) {
    int row = r0 + wr * 64 + m * 16 + ((lane >> 4) << 2);
    #pragma unroll
    for (int n = 0; n < 4; n++) {
      int col = wc * 64 + n * 16 + (lane & 15);
      float bv = bias[col];
      #pragma unroll
      for (int q = 0; q < 4; q++) {
        float v = acc[m][n][q] + bv;
        if (RELU) v = fmaxf(v, 0.f);
        C[(size_t)(row + q) * 256 + col] = f2bf(v);
      }
    }
  }
}

// ---------------- row LayerNorm (in place, bf16), one wave per row -------------
__global__ void lnrow_kernel(ushort* t, const float* g, const float* bta) {
  int row = blockIdx.x * 4 + (threadIdx.x >> 6);
  int lane = threadIdx.x & 63;
  ushort* p = t + (size_t)row * 256 + lane * 4;
  uint2 v = *reinterpret_cast<const uint2*>(p);
  ushort us[4]; *reinterpret_cast<uint2*>(us) = v;
  float f[4];
  float s = 0.f, sq = 0.f;
  #pragma unroll
  for (int j = 0; j < 4; j++) { f[j] = bf2f(us[j]); s += f[j]; sq += f[j] * f[j]; }
  #pragma unroll
  for (int m = 1; m < 64; m <<= 1) { s += __shfl_xor(s, m); sq += __shfl_xor(sq, m); }
  float mean = s * (1.f / 256.f);
  float var = sq * (1.f / 256.f) - mean * mean;
  float rstd = rsqrtf(var + 1e-5f);
  float4 gv = *reinterpret_cast<const float4*>(g + lane * 4);
  float4 bv = *reinterpret_cast<const float4*>(bta + lane * 4);
  #pragma unroll
  for (int j = 0; j < 4; j++) us[j] = f2bf((f[j] - mean) * rstd * (&gv.x)[j] + (&bv.x)[j]);
  *reinterpret_cast<uint2*>(p) = *reinterpret_cast<uint2*>(us);
}

// ---------------- slot init ----------------------------------------------------
__global__ void kslots_kernel(const float* eps, const float* loc, const float* lsc, float* slots) {
  int i = blockIdx.x * 256 + threadIdx.x;    // < 65536
  int d = i & 255;
  slots[i] = loc[d] + expf(lsc[d]) * eps[i];
}

// ---------------- per-iter: slot LN + q projection (scaled), zero attn_sum -----
__global__ void ka_kernel(const float* slots, const float* sg, const float* sb,
                          const float* qw, const float* qb, ushort* qT, float* attn_sum) {
  int s = blockIdx.x;                 // 0..15 (8..15 = zero padding rows)
  int b = blockIdx.y;
  int tid = threadIdx.x;
  ushort* qrow = qT + ((size_t)b * 16 + s) * 256;
  if (s >= 8) { qrow[tid] = 0; return; }
  __shared__ float sn[256];
  float xv = slots[((size_t)b * 8 + s) * 256 + tid];
  float a = xv, sq = xv * xv;
  blk_reduce2(a, sq);
  float mean = a * (1.f / 256.f);
  float var = sq * (1.f / 256.f) - mean * mean;
  float rstd = rsqrtf(var + 1e-5f);
  sn[tid] = (xv - mean) * rstd * sg[tid] + sb[tid];
  __syncthreads();
  float acc = qb[tid];
  for (int d = 0; d < 256; d++) acc = fmaf(sn[d], qw[(size_t)d * 256 + tid], acc);
  qrow[tid] = f2bf(acc * 0.0625f);    // fold SCALE = 1/16
  if (tid == 0) attn_sum[b * 8 + s] = 0.f;
}

// ---------------- per-iter: dots (MFMA) + slot-softmax + attn_sum; zero upd ----
__global__ __launch_bounds__(256) void kb_kernel(const ushort* __restrict__ kmat,
                                                 const ushort* __restrict__ qT,
                                                 float* __restrict__ attn,
                                                 float* __restrict__ attn_sum,
                                                 float* __restrict__ upd) {
  int tcx = blockIdx.x;               // 0..15 (256 tokens each)
  int b = blockIdx.y;
  int tid = threadIdx.x, w = tid >> 6, lane = tid & 63;
  if (tid < 128) upd[(size_t)b * 2048 + tcx * 128 + tid] = 0.f;
  __shared__ ushort Ks[256 * 72];
  const ushort* kbase = kmat + ((size_t)b * 4096 + tcx * 256) * 256;
  const ushort* qbase = qT + (size_t)b * 16 * 256;
  f32x4 acc[4];
  #pragma unroll
  for (int m = 0; m < 4; m++) acc[m] = (f32x4)(0.f);
  for (int ks = 0; ks < 4; ks++) {
    int k0 = ks * 64;
    __syncthreads();
    #pragma unroll
    for (int i = 0; i < 8; i++) {
      int idx = tid + i * 256;
      int r = idx >> 3, cc = idx & 7;
      *reinterpret_cast<uint4*>(&Ks[r * 72 + cc * 8]) =
          *reinterpret_cast<const uint4*>(kbase + (size_t)r * 256 + k0 + cc * 8);
    }
    __syncthreads();
    #pragma unroll
    for (int ksub = 0; ksub < 2; ksub++) {
      int kk = ksub * 32 + (lane >> 4) * 8;
      short8 bq = *reinterpret_cast<const short8*>(qbase + (lane & 15) * 256 + k0 + kk);
      #pragma unroll
      for (int m = 0; m < 4; m++) {
        short8 af = *reinterpret_cast<const short8*>(&Ks[(w * 64 + m * 16 + (lane & 15)) * 72 + kk]);
        acc[m] = __builtin_amdgcn_mfma_f32_16x16x32_bf16(af, bq, acc[m], 0, 0, 0);
      }
    }
  }
  // softmax over slots (cols of the fragment) per token row
  bool valid = (lane & 15) < 8;
  float lsum = 0.f;
  int srow = (lane >> 4) * 4;
  #pragma unroll
  for (int m = 0; m < 4; m++) {
    #pragma unroll
    for (int q = 0; q < 4; q++) {
      float d = acc[m][q];
      float mv = valid ? d : -1e30f;
      #pragma unroll
      for (int msk = 1; msk < 16; msk <<= 1) mv = fmaxf(mv, __shfl_xor(mv, msk));
      float e = valid ? expf(d - mv) : 0.f;
      float ssum = e;
      #pragma unroll
      for (int msk = 1; msk < 16; msk <<= 1) ssum += __shfl_xor(ssum, msk);
      if (valid) {
        float av = e / ssum + 1e-8f;
        int t = tcx * 256 + w * 64 + m * 16 + srow + q;
        attn[((size_t)b * 4096 + t) * 8 + (lane & 15)] = av;
        lsum += av;
      }
    }
  }
  lsum += __shfl_xor(lsum, 16);
  lsum += __shfl_xor(lsum, 32);
  __shared__ float wsum[4][16];
  if (lane < 16) wsum[w][lane] = lsum;
  __syncthreads();
  if (tid < 8) {
    float tot = wsum[0][tid] + wsum[1][tid] + wsum[2][tid] + wsum[3][tid];
    atomicAdd(&attn_sum[b * 8 + tid], tot);
  }
}

// ---------------- per-iter: upd = attn @ v (partial per token chunk) -----------
__global__ __launch_bounds__(256) void kc_kernel(const ushort* __restrict__ vmat,
                                                 const float* __restrict__ attn,
                                                 float* __restrict__ upd) {
  int tcx = blockIdx.x;               // 0..7 (512 tokens each)
  int b = blockIdx.y;
  int tid = threadIdx.x, g = tid >> 6, lane = tid & 63;
  __shared__ float at[64][8];
  __shared__ float red[4][8][256];
  float acc[8][4];
  #pragma unroll
  for (int s = 0; s < 8; s++)
    #pragma unroll
    for (int j = 0; j < 4; j++) acc[s][j] = 0.f;
  const ushort* vb = vmat + ((size_t)b * 4096 + tcx * 512) * 256;
  const float* ab = attn + ((size_t)b * 4096 + tcx * 512) * 8;
  for (int tile = 0; tile < 8; tile++) {
    __syncthreads();
    if (tid < 128)
      *reinterpret_cast<float4*>(&at[0][0] + tid * 4) =
          *reinterpret_cast<const float4*>(ab + tile * 512 + tid * 4);
    __syncthreads();
    for (int ti = 0; ti < 16; ti++) {
      int tl = g * 16 + ti;
      uint2 vv = *reinterpret_cast<const uint2*>(vb + (size_t)(tile * 64 + tl) * 256 + lane * 4);
      ushort us[4]; *reinterpret_cast<uint2*>(us) = vv;
      float vf[4];
      #pragma unroll
      for (int j = 0; j < 4; j++) vf[j] = bf2f(us[j]);
      #pragma unroll
      for (int s = 0; s < 8; s++) {
        float a = at[tl][s];
        #pragma unroll
        for (int j = 0; j < 4; j++) acc[s][j] = fmaf(a, vf[j], acc[s][j]);
      }
    }
  }
  #pragma unroll
  for (int s = 0; s < 8; s++) {
    float4 v4; v4.x = acc[s][0]; v4.y = acc[s][1]; v4.z = acc[s][2]; v4.w = acc[s][3];
    *reinterpret_cast<float4*>(&red[g][s][lane * 4]) = v4;
  }
  __syncthreads();
  #pragma unroll
  for (int i = 0; i < 8; i++) {
    int idx = tid + i * 256;
    int s = idx >> 8, d = idx & 255;
    float sum = red[0][s][d] + red[1][s][d] + red[2][s][d] + red[3][s][d];
    atomicAdd(&upd[((size_t)b * 8 + s) * 256 + d], sum);
  }
}

// ---------------- per-iter: GRU + residual MLP slot update ---------------------
__global__ void kd_kernel(const float* __restrict__ upd, const float* __restrict__ attn_sum,
                          float* __restrict__ slots,
                          const float* __restrict__ wih, const float* __restrict__ whh,
                          const float* __restrict__ bih, const float* __restrict__ bhh,
                          const float* __restrict__ pre_g, const float* __restrict__ pre_b,
                          const float* __restrict__ w1, const float* __restrict__ b1,
                          const float* __restrict__ w2, const float* __restrict__ b2,
                          float* __restrict__ out_extra) {
  int s = blockIdx.x, b = blockIdx.y;
  int tid = threadIdx.x;
  size_t base = ((size_t)b * 8 + s) * 256;
  __shared__ float u[256], p[256], f1[256], f2[256];
  float inv = 1.f / attn_sum[b * 8 + s];
  u[tid] = upd[base + tid] * inv;
  p[tid] = slots[base + tid];
  __syncthreads();
  float gi0 = bih[tid], gi1 = bih[256 + tid], gi2 = bih[512 + tid];
  float gh0 = bhh[tid], gh1 = bhh[256 + tid], gh2 = bhh[512 + tid];
  for (int d = 0; d < 256; d++) {
    float ud = u[d], pd = p[d];
    const float* wi = wih + (size_t)d * 768 + tid;
    const float* wh = whh + (size_t)d * 768 + tid;
    gi0 = fmaf(ud, wi[0], gi0); gi1 = fmaf(ud, wi[256], gi1); gi2 = fmaf(ud, wi[512], gi2);
    gh0 = fmaf(pd, wh[0], gh0); gh1 = fmaf(pd, wh[256], gh1); gh2 = fmaf(pd, wh[512], gh2);
  }
  float r = 1.f / (1.f + expf(-(gi0 + gh0)));
  float z = 1.f / (1.f + expf(-(gi1 + gh1)));
  float n = tanhf(gi2 + r * gh2);
  float hv = (1.f - z) * n + z * p[tid];
  float a = hv, sq = hv * hv;
  blk_reduce2(a, sq);
  float mean = a * (1.f / 256.f);
  float var = sq * (1.f / 256.f) - mean * mean;
  float rstd = rsqrtf(var + 1e-5f);
  f1[tid] = (hv - mean) * rstd * pre_g[tid] + pre_b[tid];
  __syncthreads();
  float acc1 = b1[tid];
  for (int d = 0; d < 256; d++) acc1 = fmaf(f1[d], w1[(size_t)d * 256 + tid], acc1);
  acc1 = fmaxf(acc1, 0.f);
  f2[tid] = acc1;
  __syncthreads();
  float acc2 = b2[tid];
  for (int d = 0; d < 256; d++) acc2 = fmaf(f2[d], w2[(size_t)d * 256 + tid], acc2);
  acc2 = fmaxf(acc2, 0.f);
  float res = hv + acc2;
  slots[base + tid] = res;
  if (out_extra) out_extra[base + tid] = res;
}

extern "C" void kernel_launch(void* const* d_in, const int* in_sizes, int n_in,
                              void* d_out, int out_size, void* d_ws, size_t ws_size,
                              hipStream_t stream) {
  const float* x         = (const float*)d_in[0];
  const float* eps_noise = (const float*)d_in[1];
  const float* pos_w     = (const float*)d_in[2];
  const float* pos_b     = (const float*)d_in[3];
  const float* enc_g     = (const float*)d_in[4];
  const float* enc_b     = (const float*)d_in[5];
  const float* fm_w1     = (const float*)d_in[6];
  const float* fm_b1     = (const float*)d_in[7];
  const float* fm_w2     = (const float*)d_in[8];
  const float* fm_b2     = (const float*)d_in[9];
  const float* in_g      = (const float*)d_in[10];
  const float* in_b      = (const float*)d_in[11];
  const float* q_w       = (const float*)d_in[12];
  const float* q_b       = (const float*)d_in[13];
  const float* k_w       = (const float*)d_in[14];
  const float* k_b       = (const float*)d_in[15];
  const float* v_w       = (const float*)d_in[16];
  const float* v_b       = (const float*)d_in[17];
  const float* gru_wih   = (const float*)d_in[18];
  const float* gru_whh   = (const float*)d_in[19];
  const float* gru_bih   = (const float*)d_in[20];
  const float* gru_bhh   = (const float*)d_in[21];
  const float* pre_g     = (const float*)d_in[22];
  const float* pre_b     = (const float*)d_in[23];
  const float* st_w1     = (const float*)d_in[24];
  const float* st_b1     = (const float*)d_in[25];
  const float* st_w2     = (const float*)d_in[26];
  const float* st_b2     = (const float*)d_in[27];
  const float* slot_g    = (const float*)d_in[28];
  const float* slot_b    = (const float*)d_in[29];
  const float* slots_loc = (const float*)d_in[30];
  const float* slots_lsc = (const float*)d_in[31];
  (void)in_sizes; (void)n_in; (void)out_size;

  char* ws = (char*)d_ws;
  const size_t OFF_BUFB   = 67108864;                 // bufA at 0 (64 MB)
  const size_t OFF_WT     = 134217728;                // 512 KB
  const size_t OFF_QT     = OFF_WT + 524288;          // 256 KB
  const size_t OFF_ATTN   = OFF_QT + 262144;          // 4 MB
  const size_t OFF_SLOTS  = OFF_ATTN + 4194304;       // 256 KB
  const size_t OFF_UPD    = OFF_SLOTS + 262144;       // 256 KB
  const size_t OFF_BSTATS = OFF_UPD + 262144;         // 256 B
  const size_t OFF_ASUM   = OFF_BSTATS + 256;         // 1 KB
  const size_t NEED       = OFF_ASUM + 1024;
  if (ws_size < NEED) return;

  ushort* bufA   = (ushort*)ws;
  ushort* bufB   = (ushort*)(ws + OFF_BUFB);
  ushort* wT     = (ushort*)(ws + OFF_WT);
  ushort* qT     = (ushort*)(ws + OFF_QT);
  float* attn    = (float*)(ws + OFF_ATTN);
  float* slots   = (float*)(ws + OFF_SLOTS);
  float* upd     = (float*)(ws + OFF_UPD);
  float* bstats  = (float*)(ws + OFF_BSTATS);
  float* asum    = (float*)(ws + OFF_ASUM);

  kw_kernel<<<dim3(16, 4), 256, 0, stream>>>(fm_w1, fm_w2, k_w, v_w, wT, bstats);
  k1_stats<<<dim3(64, 32), 256, 0, stream>>>(x, pos_w, pos_b, bstats);
  k2_tokens<<<dim3(64, 4, 32), 256, 0, stream>>>(x, pos_w, pos_b, enc_g, enc_b, bstats, bufA);
  gemm_kernel<true><<<1024, 512, 0, stream>>>(bufA, wT, fm_b1, bufA);
  gemm_kernel<true><<<1024, 512, 0, stream>>>(bufA, wT + 65536, fm_b2, bufA);
  lnrow_kernel<<<32768, 256, 0, stream>>>(bufA, in_g, in_b);
  gemm_kernel<false><<<1024, 512, 0, stream>>>(bufA, wT + 131072, k_b, bufB);   // k
  gemm_kernel<false><<<1024, 512, 0, stream>>>(bufA, wT + 196608, v_b, bufA);   // v (in place)
  kslots_kernel<<<256, 256, 0, stream>>>(eps_noise, slots_loc, slots_lsc, slots);
  for (int it = 0; it < 3; it++) {
    ka_kernel<<<dim3(16, 32), 256, 0, stream>>>(slots, slot_g, slot_b, q_w, q_b, qT, asum);
    kb_kernel<<<dim3(16, 32), 256, 0, stream>>>(bufB, qT, attn, asum, upd);
    kc_kernel<<<dim3(8, 32), 256, 0, stream>>>(bufA, attn, upd);
    kd_kernel<<<dim3(8, 32), 256, 0, stream>>>(upd, asum, slots,
        gru_wih, gru_whh, gru_bih, gru_bhh, pre_g, pre_b,
        st_w1, st_b1, st_w2, st_b2, (it == 2) ? (float*)d_out : nullptr);
  }
}